// Round 1
// baseline (570.076 us; speedup 1.0000x reference)
//
#include <hip/hip_runtime.h>
#include <stdint.h>

#define DIM 512
#define BM  128
#define BK  128
#define DT  32
#define LDSX (BM + 4)

typedef __attribute__((ext_vector_type(8))) _Float16 f16x8;
typedef __attribute__((ext_vector_type(4))) _Float16 f16x4;
typedef __attribute__((ext_vector_type(4))) float f32x4;

__device__ __forceinline__ void async_cp16(const void* g, void* l) {
    __builtin_amdgcn_global_load_lds(
        (const __attribute__((address_space(1))) unsigned int*)g,
        (__attribute__((address_space(3))) unsigned int*)l, 16, 0, 0);
}

// ---------- e_sq: one wave per code (fp32, matches verify path) ----------
__global__ __launch_bounds__(256)
void esq_kernel(const float* __restrict__ embed, float* __restrict__ e_sq, int K) {
    int wave = (blockIdx.x * blockDim.x + threadIdx.x) >> 6;
    int lane = threadIdx.x & 63;
    if (wave >= K) return;
    const float* row = embed + (size_t)wave * DIM;
    float s = 0.f;
#pragma unroll
    for (int j = 0; j < DIM / 64; ++j) { float v = row[lane + 64 * j]; s += v * v; }
#pragma unroll
    for (int off = 32; off; off >>= 1) s += __shfl_down(s, off, 64);
    if (lane == 0) e_sq[wave] = s;
}

// ---------- fp32 -> fp16 convert (embed only now) ----------
__global__ __launch_bounds__(256)
void cvt_f16_kernel(const float* __restrict__ src, _Float16* __restrict__ dst, int n4) {
    int i = blockIdx.x * 256 + threadIdx.x;
    if (i >= n4) return;
    float4 v = ((const float4*)src)[i];
    f16x4 h;
    h[0] = (_Float16)v.x; h[1] = (_Float16)v.y; h[2] = (_Float16)v.z; h[3] = (_Float16)v.w;
    ((f16x4*)dst)[i] = h;
}

// ---------- A-in-registers fp16 MFMA scan over all K codes ----------
// Each block: 128 rows (4 waves x 32 rows). x fragments held in VGPRs (converted
// in-register from fp32). e streamed through double-buffered LDS (2 x 32KB groups
// of 64 codes x 256 halfs), 2-phase prefetch pipeline: stage(next) || MFMA(cur).
// Per-lane top-2 via packed keys: (float_bits(score+1024) & ~2047) | code_idx.
template<int GV>
__device__ __forceinline__ void compute_group(const _Float16* ebuf,
    const f16x8 (&ah)[2][16], f32x4 (&acc)[2][4], int quad, int l15)
{
#pragma unroll
    for (int dtl = 0; dtl < 4; ++dtl) {
#pragma unroll
        for (int kwi = 0; kwi < 2; ++kwi) {
            const int pch = (kwi * 4 + quad) ^ (l15 & 7);
            f16x8 bh[4];
#pragma unroll
            for (int nt = 0; nt < 4; ++nt)
                bh[nt] = *(const f16x8*)(ebuf + dtl * 4096 + (nt * 16 + l15) * 64 + pch * 8);
#pragma unroll
            for (int mt = 0; mt < 2; ++mt)
#pragma unroll
                for (int nt = 0; nt < 4; ++nt)
                    acc[mt][nt] = __builtin_amdgcn_mfma_f32_16x16x32_f16(
                        ah[mt][(GV * 4 + dtl) * 2 + kwi], bh[nt], acc[mt][nt], 0, 0, 0);
        }
    }
}

__global__ __launch_bounds__(256, 2)
void vq_reg_kernel(const float* __restrict__ x, const _Float16* __restrict__ eh,
                   const float* __restrict__ e_sq, int* __restrict__ cand)
{
    // LDS: EB double buffer 2x32768 B + esq 8192 B = 73728 B.
    // reduction rk[128][33] (16896 B) aliases EB after the main loop.
    __shared__ __align__(16) char smem[73728];
    _Float16* EB = (_Float16*)smem;
    const float* esq_l = (const float*)(smem + 65536);
    uint32_t* rk = (uint32_t*)smem;

    const int tid  = threadIdx.x;
    const int w    = tid >> 6, lane = tid & 63;
    const int quad = lane >> 4, l15 = lane & 15;
    const int r0   = blockIdx.x * 128;
    const int wrow = r0 + w * 32;

    // per-thread staging offsets (halfs) within one (kt,g) 32KB group.
    // LDS slot s = w*512 + i*64 + lane; layout [dtl][row][chunk] with chunk
    // XOR-swizzled by row&7 (global side pre-swizzled, LDS linear).
    uint32_t goff[8];
#pragma unroll
    for (int i = 0; i < 8; ++i) {
        const int s   = w * 512 + i * 64 + lane;
        const int dtl = s >> 9;
        const int rr  = (s >> 3) & 63;
        const int lch = (s & 7) ^ (rr & 7);
        goff[i] = (uint32_t)(rr * 512 + dtl * 64 + lch * 8);
    }

    // ---- prologue: stage e_sq (8KB) + group(kt=0,g=0)->buf0; load+convert A ----
#pragma unroll
    for (int i = 0; i < 2; ++i) {
        const int sb = w * 128 + i * 64;
        async_cp16(e_sq + (size_t)(sb + lane) * 4, smem + 65536 + sb * 16);
    }
#pragma unroll
    for (int i = 0; i < 8; ++i)
        async_cp16(eh + goff[i], smem + (w * 512 + i * 64) * 16);

    f16x8 ah[2][16];
#pragma unroll
    for (int mt = 0; mt < 2; ++mt) {
        const float* xr = x + (size_t)(wrow + mt * 16 + l15) * DIM + quad * 8;
#pragma unroll
        for (int kw = 0; kw < 16; ++kw) {
            const float4 a0 = *(const float4*)(xr + kw * 32);
            const float4 a1 = *(const float4*)(xr + kw * 32 + 4);
            f16x8 h;
            h[0] = (_Float16)a0.x; h[1] = (_Float16)a0.y;
            h[2] = (_Float16)a0.z; h[3] = (_Float16)a0.w;
            h[4] = (_Float16)a1.x; h[5] = (_Float16)a1.y;
            h[6] = (_Float16)a1.z; h[7] = (_Float16)a1.w;
            ah[mt][kw] = h;
        }
    }

    uint32_t b1[8], b2[8];
#pragma unroll
    for (int i = 0; i < 8; ++i) { b1[i] = 0xFFFFFFFFu; b2[i] = 0xFFFFFFFFu; }

    __syncthreads();

    for (int kt = 0; kt < 32; ++kt) {
        f32x4 acc[2][4];
#pragma unroll
        for (int mt = 0; mt < 2; ++mt)
#pragma unroll
            for (int nt = 0; nt < 4; ++nt)
#pragma unroll
                for (int r = 0; r < 4; ++r) acc[mt][nt][r] = 0.f;

        const size_t kb = (size_t)kt * 32768;

        // phase 0: stage (kt,g=1)->buf1 while computing g=0 from buf0
#pragma unroll
        for (int i = 0; i < 8; ++i)
            async_cp16(eh + kb + 256 + goff[i], smem + 32768 + (w * 512 + i * 64) * 16);
        compute_group<0>(EB, ah, acc, quad, l15);
        __syncthreads();

        // phase 1: stage (kt+1,g=0)->buf0 while computing g=1 from buf1
        if (kt + 1 < 32) {
#pragma unroll
            for (int i = 0; i < 8; ++i)
                async_cp16(eh + kb + 32768 + goff[i], smem + (w * 512 + i * 64) * 16);
        }
        compute_group<1>(EB + 16384, ah, acc, quad, l15);
        __syncthreads();

        // selection: packed-key top-2 per lane per row-slot (scores > 0 by construction)
#pragma unroll
        for (int nt = 0; nt < 4; ++nt) {
            const int c = kt * 64 + nt * 16 + l15;
            const float eqb = esq_l[c] + 1024.0f;
#pragma unroll
            for (int mt = 0; mt < 2; ++mt)
#pragma unroll
                for (int r = 0; r < 4; ++r) {
                    const float v = fmaf(-2.0f, acc[mt][nt][r], eqb);
                    const uint32_t u = (__float_as_uint(v) & 0xFFFFF800u) | (uint32_t)c;
                    const int s = mt * 4 + r;
                    const uint32_t mx = u > b1[s] ? u : b1[s];
                    b2[s] = mx < b2[s] ? mx : b2[s];   // second-smallest = min(max(u,b1),b2)
                    b1[s] = u < b1[s] ? u : b1[s];
                }
        }
    }

    // ---- block reduction: 32 keys per row -> top-4 codes ----
#pragma unroll
    for (int mt = 0; mt < 2; ++mt)
#pragma unroll
        for (int r = 0; r < 4; ++r) {
            const int row = w * 32 + mt * 16 + quad * 4 + r;
            const int s = mt * 4 + r;
            rk[row * 33 + l15 * 2]     = b1[s];
            rk[row * 33 + l15 * 2 + 1] = b2[s];
        }
    __syncthreads();
    if (tid < 128) {
        uint32_t t0 = 0xFFFFFFFFu, t1 = t0, t2 = t0, t3 = t0;
        for (int e = 0; e < 32; ++e) {
            const uint32_t u = rk[tid * 33 + e];
            if (u < t3) {
                if (u < t0)      { t3 = t2; t2 = t1; t1 = t0; t0 = u; }
                else if (u < t1) { t3 = t2; t2 = t1; t1 = u; }
                else if (u < t2) { t3 = t2; t2 = u; }
                else               t3 = u;
            }
        }
        int4 c4;
        c4.x = (int)(t0 & 2047u); c4.y = (int)(t1 & 2047u);
        c4.z = (int)(t2 & 2047u); c4.w = (int)(t3 & 2047u);
        *(int4*)(cand + (size_t)(r0 + tid) * 4) = c4;
    }
}

// ---------- exact fp32 re-score of 4 candidates + fused decode gather ----------
__global__ __launch_bounds__(256)
void verify_gather4_kernel(const float* __restrict__ x, const float* __restrict__ embed,
                           const float* __restrict__ e_sq, const int* __restrict__ cand,
                           float* __restrict__ out_idx, float* __restrict__ out_q) {
    const int row  = blockIdx.x * 4 + (threadIdx.x >> 6);
    const int lane = threadIdx.x & 63;
    const float4* xr = (const float4*)(x + (size_t)row * DIM);
    const float4 xv0 = xr[lane];
    const float4 xv1 = xr[lane + 64];
    const int4 cc = *(const int4*)(cand + (size_t)row * 4);
    const int cs[4] = {cc.x, cc.y, cc.z, cc.w};
    float best = 3.4e38f;
    int   bi   = 0x7fffffff;
    float4 g0{}, g1{};
#pragma unroll
    for (int k = 0; k < 4; ++k) {
        const int c = cs[k];
        const float4* er = (const float4*)(embed + (size_t)c * DIM);
        const float4 e0 = er[lane];
        const float4 e1 = er[lane + 64];
        float d = xv0.x * e0.x + xv0.y * e0.y + xv0.z * e0.z + xv0.w * e0.w
                + xv1.x * e1.x + xv1.y * e1.y + xv1.z * e1.z + xv1.w * e1.w;
#pragma unroll
        for (int off = 32; off; off >>= 1) d += __shfl_xor(d, off, 64);
        const float s = e_sq[c] - 2.0f * d;
        const bool better = (s < best) || (s == best && c < bi);
        best = better ? s : best;
        bi   = better ? c : bi;
        g0 = better ? e0 : g0;
        g1 = better ? e1 : g1;
    }
    if (lane == 0) out_idx[row] = (float)bi;
    float4* oq = (float4*)(out_q + (size_t)row * DIM);
    oq[lane]      = g0;
    oq[lane + 64] = g1;
}

// ================= fallback (fp32 path, used if d_ws too small) =================
__global__ __launch_bounds__(256)
void vq_argmin_kernel(const float* __restrict__ x, const float* __restrict__ embed,
                      const float* __restrict__ e_sq, float* __restrict__ out_idx,
                      int N, int K) {
    __shared__ float xs[DT * LDSX];
    __shared__ float es[DT * LDSX];
    __shared__ float sval[BM * 17];
    __shared__ int   sidx[BM * 17];
    const int tid = threadIdx.x;
    const int tx = tid & 15, ty = tid >> 4;
    const int r0 = blockIdx.x * BM;
    float best_val[8]; int best_idx[8];
#pragma unroll
    for (int i = 0; i < 8; ++i) { best_val[i] = 3.4e38f; best_idx[i] = 0; }
    const int nkt = K / BK;
    for (int kt = 0; kt < nkt; ++kt) {
        float acc[8][8];
#pragma unroll
        for (int i = 0; i < 8; ++i)
#pragma unroll
            for (int j = 0; j < 8; ++j) acc[i][j] = 0.f;
        for (int dt = 0; dt < DIM / DT; ++dt) {
            __syncthreads();
#pragma unroll
            for (int k = 0; k < 4; ++k) {
                int l = tid + k * 256, row = l >> 3, q = l & 7;
                const float4 v = *(const float4*)(x + (size_t)(r0 + row) * DIM + dt * DT + q * 4);
                xs[(q * 4 + 0) * LDSX + row] = v.x; xs[(q * 4 + 1) * LDSX + row] = v.y;
                xs[(q * 4 + 2) * LDSX + row] = v.z; xs[(q * 4 + 3) * LDSX + row] = v.w;
            }
#pragma unroll
            for (int k = 0; k < 4; ++k) {
                int l = tid + k * 256, row = l >> 3, q = l & 7;
                const float4 v = *(const float4*)(embed + (size_t)(kt * BK + row) * DIM + dt * DT + q * 4);
                es[(q * 4 + 0) * LDSX + row] = v.x; es[(q * 4 + 1) * LDSX + row] = v.y;
                es[(q * 4 + 2) * LDSX + row] = v.z; es[(q * 4 + 3) * LDSX + row] = v.w;
            }
            __syncthreads();
#pragma unroll
            for (int d = 0; d < DT; ++d) {
                const float4 a0 = *(const float4*)&xs[d * LDSX + 4 * ty];
                const float4 a1 = *(const float4*)&xs[d * LDSX + 4 * ty + 64];
                const float4 b0 = *(const float4*)&es[d * LDSX + 4 * tx];
                const float4 b1 = *(const float4*)&es[d * LDSX + 4 * tx + 64];
                const float a[8] = {a0.x, a0.y, a0.z, a0.w, a1.x, a1.y, a1.z, a1.w};
                const float b[8] = {b0.x, b0.y, b0.z, b0.w, b1.x, b1.y, b1.z, b1.w};
#pragma unroll
                for (int i = 0; i < 8; ++i)
#pragma unroll
                    for (int j = 0; j < 8; ++j) acc[i][j] += a[i] * b[j];
            }
        }
#pragma unroll
        for (int j = 0; j < 8; ++j) {
            const int c = kt * BK + 4 * tx + (j & 3) + 64 * (j >> 2);
            const float eq = e_sq[c];
#pragma unroll
            for (int i = 0; i < 8; ++i) {
                const float s = eq - 2.0f * acc[i][j];
                if (s < best_val[i]) { best_val[i] = s; best_idx[i] = c; }
            }
        }
    }
    __syncthreads();
#pragma unroll
    for (int i = 0; i < 8; ++i) {
        const int r = 4 * ty + (i & 3) + 64 * (i >> 2);
        sval[r * 17 + tx] = best_val[i]; sidx[r * 17 + tx] = best_idx[i];
    }
    __syncthreads();
    if (tid < BM) {
        float bv = sval[tid * 17 + 0]; int bi = sidx[tid * 17 + 0];
#pragma unroll
        for (int t = 1; t < 16; ++t) {
            const float v = sval[tid * 17 + t]; const int ix = sidx[tid * 17 + t];
            if (v < bv || (v == bv && ix < bi)) { bv = v; bi = ix; }
        }
        out_idx[r0 + tid] = (float)bi;
    }
}

__global__ __launch_bounds__(256)
void gather_kernel(const float* __restrict__ embed, const float* __restrict__ idx_f,
                   float* __restrict__ out_q) {
    const int row = blockIdx.x * 2 + (threadIdx.x >> 7);
    const int c = threadIdx.x & 127;
    const int idx = (int)idx_f[row];
    const float4 v = *(const float4*)(embed + (size_t)idx * DIM + c * 4);
    *(float4*)(out_q + (size_t)row * DIM + c * 4) = v;
}

// ================= launch =================
extern "C" void kernel_launch(void* const* d_in, const int* in_sizes, int n_in,
                              void* d_out, int out_size, void* d_ws, size_t ws_size,
                              hipStream_t stream) {
    const float* x     = (const float*)d_in[0];
    const float* embed = (const float*)d_in[1];
    const int N = in_sizes[0] / DIM;   // 65536
    const int K = in_sizes[1] / DIM;   // 2048

    float* out_idx = (float*)d_out;
    float* out_q   = (float*)d_out + N;
    char* ws = (char*)d_ws;

    const size_t off_cand = 8192;                              // after e_sq (K*4)
    const size_t off_eh   = off_cand + (size_t)N * 16;         // cand: N*4 ints
    const size_t need     = off_eh + (size_t)K * DIM * 2;      // eh: K*DIM halfs

    float* e_sq = (float*)ws;
    esq_kernel<<<(K + 3) / 4, 256, 0, stream>>>(embed, e_sq, K);

    if (ws_size >= need && K == 2048 && (N % 128) == 0) {
        _Float16* eh = (_Float16*)(ws + off_eh);
        int* cand = (int*)(ws + off_cand);
        cvt_f16_kernel<<<(K * DIM / 4 + 255) / 256, 256, 0, stream>>>(embed, eh, K * DIM / 4);
        vq_reg_kernel<<<N / 128, 256, 0, stream>>>(x, eh, e_sq, cand);
        verify_gather4_kernel<<<N / 4, 256, 0, stream>>>(x, embed, e_sq, cand, out_idx, out_q);
    } else {
        vq_argmin_kernel<<<N / BM, 256, 0, stream>>>(x, embed, e_sq, out_idx, N, K);
        gather_kernel<<<N / 2, 256, 0, stream>>>(embed, out_idx, out_q);
    }
}

// Round 3
// 357.806 us; speedup vs baseline: 1.5933x; 1.5933x over previous
//
#include <hip/hip_runtime.h>
#include <stdint.h>

#define DIM 512
#define BM  128
#define BK  128
#define DT  32
#define LDSX (BM + 4)

typedef __attribute__((ext_vector_type(8))) _Float16 f16x8;
typedef __attribute__((ext_vector_type(4))) _Float16 f16x4;
typedef __attribute__((ext_vector_type(4))) float f32x4;

__device__ __forceinline__ void async_cp16(const void* g, void* l) {
    __builtin_amdgcn_global_load_lds(
        (const __attribute__((address_space(1))) unsigned int*)g,
        (__attribute__((address_space(3))) unsigned int*)l, 16, 0, 0);
}

// ---------- e_sq: one wave per code (fp32, matches verify path) ----------
__global__ __launch_bounds__(256)
void esq_kernel(const float* __restrict__ embed, float* __restrict__ e_sq, int K) {
    int wave = (blockIdx.x * blockDim.x + threadIdx.x) >> 6;
    int lane = threadIdx.x & 63;
    if (wave >= K) return;
    const float* row = embed + (size_t)wave * DIM;
    float s = 0.f;
#pragma unroll
    for (int j = 0; j < DIM / 64; ++j) { float v = row[lane + 64 * j]; s += v * v; }
#pragma unroll
    for (int off = 32; off; off >>= 1) s += __shfl_down(s, off, 64);
    if (lane == 0) e_sq[wave] = s;
}

// ---------- fp32 -> fp16 convert (embed only) ----------
__global__ __launch_bounds__(256)
void cvt_f16_kernel(const float* __restrict__ src, _Float16* __restrict__ dst, int n4) {
    int i = blockIdx.x * 256 + threadIdx.x;
    if (i >= n4) return;
    float4 v = ((const float4*)src)[i];
    f16x4 h;
    h[0] = (_Float16)v.x; h[1] = (_Float16)v.y; h[2] = (_Float16)v.z; h[3] = (_Float16)v.w;
    ((f16x4*)dst)[i] = h;
}

// ---------- A-in-registers fp16 MFMA scan over all K codes ----------
// Each block: 128 rows (4 waves x 32 rows). x fragments held in VGPRs (converted
// in-register from fp32). e streamed through double-buffered LDS (2 x 32KB groups
// of 64 codes x 256 halfs), 2-phase prefetch pipeline: stage(next) || MFMA(cur).
// Per-lane top-2 via packed keys: (float_bits(score+1024) & ~2047) | code_idx.
template<int GV>
__device__ __forceinline__ void compute_group(const _Float16* ebuf,
    const f16x8 (&ah)[2][16], f32x4 (&acc)[2][4], int quad, int l15)
{
#pragma unroll
    for (int dtl = 0; dtl < 4; ++dtl) {
#pragma unroll
        for (int kwi = 0; kwi < 2; ++kwi) {
            const int pch = (kwi * 4 + quad) ^ (l15 & 7);
            f16x8 bh[4];
#pragma unroll
            for (int nt = 0; nt < 4; ++nt)
                bh[nt] = *(const f16x8*)(ebuf + dtl * 4096 + (nt * 16 + l15) * 64 + pch * 8);
#pragma unroll
            for (int mt = 0; mt < 2; ++mt)
#pragma unroll
                for (int nt = 0; nt < 4; ++nt)
                    acc[mt][nt] = __builtin_amdgcn_mfma_f32_16x16x32_f16(
                        ah[mt][(GV * 4 + dtl) * 2 + kwi], bh[nt], acc[mt][nt], 0, 0, 0);
        }
    }
}

__global__ __launch_bounds__(256, 2)
void vq_reg_kernel(const float* __restrict__ x, const _Float16* __restrict__ eh,
                   const float* __restrict__ e_sq, int* __restrict__ cand)
{
    // LDS: EB double buffer 2x32768 B + esq 8192 B = 73728 B.
    // reduction rk[128][33] (16896 B) aliases EB after the main loop.
    __shared__ __align__(16) char smem[73728];
    _Float16* EB = (_Float16*)smem;
    const float* esq_l = (const float*)(smem + 65536);
    uint32_t* rk = (uint32_t*)smem;

    const int tid  = threadIdx.x;
    const int w    = tid >> 6, lane = tid & 63;
    const int quad = lane >> 4, l15 = lane & 15;
    const int r0   = blockIdx.x * 128;
    const int wrow = r0 + w * 32;

    // per-thread staging offsets (halfs) within one (kt,g) 32KB group.
    uint32_t goff[8];
#pragma unroll
    for (int i = 0; i < 8; ++i) {
        const int s   = w * 512 + i * 64 + lane;
        const int dtl = s >> 9;
        const int rr  = (s >> 3) & 63;
        const int lch = (s & 7) ^ (rr & 7);
        goff[i] = (uint32_t)(rr * 512 + dtl * 64 + lch * 8);
    }

    // ---- prologue: stage e_sq (8KB) + group(kt=0,g=0)->buf0; load+convert A ----
#pragma unroll
    for (int i = 0; i < 2; ++i) {
        const int sb = w * 128 + i * 64;
        async_cp16(e_sq + (size_t)(sb + lane) * 4, smem + 65536 + sb * 16);
    }
#pragma unroll
    for (int i = 0; i < 8; ++i)
        async_cp16(eh + goff[i], smem + (w * 512 + i * 64) * 16);

    f16x8 ah[2][16];
#pragma unroll
    for (int mt = 0; mt < 2; ++mt) {
        const float* xr = x + (size_t)(wrow + mt * 16 + l15) * DIM + quad * 8;
#pragma unroll
        for (int kw = 0; kw < 16; ++kw) {
            const float4 a0 = *(const float4*)(xr + kw * 32);
            const float4 a1 = *(const float4*)(xr + kw * 32 + 4);
            f16x8 h;
            h[0] = (_Float16)a0.x; h[1] = (_Float16)a0.y;
            h[2] = (_Float16)a0.z; h[3] = (_Float16)a0.w;
            h[4] = (_Float16)a1.x; h[5] = (_Float16)a1.y;
            h[6] = (_Float16)a1.z; h[7] = (_Float16)a1.w;
            ah[mt][kw] = h;
        }
    }

    uint32_t b1[8], b2[8];
#pragma unroll
    for (int i = 0; i < 8; ++i) { b1[i] = 0xFFFFFFFFu; b2[i] = 0xFFFFFFFFu; }

    __syncthreads();

    for (int kt = 0; kt < 32; ++kt) {
        f32x4 acc[2][4];
#pragma unroll
        for (int mt = 0; mt < 2; ++mt)
#pragma unroll
            for (int nt = 0; nt < 4; ++nt)
#pragma unroll
                for (int r = 0; r < 4; ++r) acc[mt][nt][r] = 0.f;

        const size_t kb = (size_t)kt * 32768;

        // phase 0: stage (kt,g=1)->buf1 while computing g=0 from buf0
#pragma unroll
        for (int i = 0; i < 8; ++i)
            async_cp16(eh + kb + 256 + goff[i], smem + 32768 + (w * 512 + i * 64) * 16);
        compute_group<0>(EB, ah, acc, quad, l15);
        __syncthreads();

        // phase 1: stage (kt+1,g=0)->buf0 while computing g=1 from buf1
        if (kt + 1 < 32) {
#pragma unroll
            for (int i = 0; i < 8; ++i)
                async_cp16(eh + kb + 32768 + goff[i], smem + (w * 512 + i * 64) * 16);
        }
        compute_group<1>(EB + 16384, ah, acc, quad, l15);
        __syncthreads();

        // selection: packed-key top-2 per lane per row-slot
#pragma unroll
        for (int nt = 0; nt < 4; ++nt) {
            const int c = kt * 64 + nt * 16 + l15;
            const float eqb = esq_l[c] + 1024.0f;
#pragma unroll
            for (int mt = 0; mt < 2; ++mt)
#pragma unroll
                for (int r = 0; r < 4; ++r) {
                    const float v = fmaf(-2.0f, acc[mt][nt][r], eqb);
                    const uint32_t u = (__float_as_uint(v) & 0xFFFFF800u) | (uint32_t)c;
                    const int s = mt * 4 + r;
                    const uint32_t mx = u > b1[s] ? u : b1[s];
                    b2[s] = mx < b2[s] ? mx : b2[s];
                    b1[s] = u < b1[s] ? u : b1[s];
                }
        }
    }

    // ---- block reduction: 32 keys per row -> top-4 codes + certainty flag ----
#pragma unroll
    for (int mt = 0; mt < 2; ++mt)
#pragma unroll
        for (int r = 0; r < 4; ++r) {
            const int row = w * 32 + mt * 16 + quad * 4 + r;
            const int s = mt * 4 + r;
            rk[row * 33 + l15 * 2]     = b1[s];
            rk[row * 33 + l15 * 2 + 1] = b2[s];
        }
    __syncthreads();
    if (tid < 128) {
        uint32_t t0 = 0xFFFFFFFFu, t1 = t0, t2 = t0, t3 = t0;
        for (int e = 0; e < 32; ++e) {
            const uint32_t u = rk[tid * 33 + e];
            if (u < t3) {
                if (u < t0)      { t3 = t2; t2 = t1; t1 = t0; t0 = u; }
                else if (u < t1) { t3 = t2; t2 = t1; t1 = u; }
                else if (u < t2) { t3 = t2; t2 = u; }
                else               t3 = u;
            }
        }
        // fp16 top-2 gap certifies top-1 (fp16 score err << 0.5; key trunc <= 0.5).
        // gap >= 1.0 -> skip exact re-score; else set bit 31 of cand.x.
        const float v0 = __uint_as_float(t0 & 0xFFFFF800u);
        const float v1 = __uint_as_float(t1 & 0xFFFFF800u);
        uint32_t c0 = t0 & 2047u;
        if (!(v1 - v0 >= 1.0f)) c0 |= 0x80000000u;
        int4 c4;
        c4.x = (int)c0;
        c4.y = (int)(t1 & 2047u);
        c4.z = (int)(t2 & 2047u);
        c4.w = (int)(t3 & 2047u);
        *(int4*)(cand + (size_t)(r0 + tid) * 4) = c4;
    }
}

// ---------- decode gather; exact fp32 re-score only for flagged rows ----------
// 4 rows per wave, 16 rows per block. Fast path: pure gather (embed is L2-resident)
// + nontemporal 2KB store. Slow path (~13% of rows): fp32 re-score of 4 candidates.
__global__ __launch_bounds__(256)
void verify_gather4_kernel(const float* __restrict__ x, const float* __restrict__ embed,
                           const float* __restrict__ e_sq, const int* __restrict__ cand,
                           float* __restrict__ out_idx, float* __restrict__ out_q) {
    const int w    = threadIdx.x >> 6;
    const int lane = threadIdx.x & 63;
    const int row0 = blockIdx.x * 16 + w * 4;
#pragma unroll
    for (int rr = 0; rr < 4; ++rr) {
        const int row = row0 + rr;
        const int4 cc = *(const int4*)(cand + (size_t)row * 4);
        f32x4* oq = (f32x4*)(out_q + (size_t)row * DIM);
        if (cc.x >= 0) {
            // certain: gather top-1 row and stream it out
            const f32x4* er = (const f32x4*)(embed + (size_t)cc.x * DIM);
            const f32x4 e0 = er[lane];
            const f32x4 e1 = er[lane + 64];
            __builtin_nontemporal_store(e0, oq + lane);
            __builtin_nontemporal_store(e1, oq + lane + 64);
            if (lane == 0) out_idx[row] = (float)cc.x;
        } else {
            const f32x4* xr = (const f32x4*)(x + (size_t)row * DIM);
            const f32x4 xv0 = __builtin_nontemporal_load(xr + lane);
            const f32x4 xv1 = __builtin_nontemporal_load(xr + lane + 64);
            const int cs[4] = {cc.x & 2047, cc.y & 2047, cc.z & 2047, cc.w & 2047};
            float best = 3.4e38f;
            int   bi   = 0x7fffffff;
            f32x4 g0 = {0.f, 0.f, 0.f, 0.f}, g1 = {0.f, 0.f, 0.f, 0.f};
#pragma unroll
            for (int k = 0; k < 4; ++k) {
                const int c = cs[k];
                const f32x4* er = (const f32x4*)(embed + (size_t)c * DIM);
                const f32x4 e0 = er[lane];
                const f32x4 e1 = er[lane + 64];
                float d = xv0[0] * e0[0] + xv0[1] * e0[1] + xv0[2] * e0[2] + xv0[3] * e0[3]
                        + xv1[0] * e1[0] + xv1[1] * e1[1] + xv1[2] * e1[2] + xv1[3] * e1[3];
#pragma unroll
                for (int off = 32; off; off >>= 1) d += __shfl_xor(d, off, 64);
                const float s = e_sq[c] - 2.0f * d;
                const bool better = (s < best) || (s == best && c < bi);
                best = better ? s : best;
                bi   = better ? c : bi;
                g0 = better ? e0 : g0;
                g1 = better ? e1 : g1;
            }
            if (lane == 0) out_idx[row] = (float)bi;
            __builtin_nontemporal_store(g0, oq + lane);
            __builtin_nontemporal_store(g1, oq + lane + 64);
        }
    }
}

// ================= fallback (fp32 path, used if d_ws too small) =================
__global__ __launch_bounds__(256)
void vq_argmin_kernel(const float* __restrict__ x, const float* __restrict__ embed,
                      const float* __restrict__ e_sq, float* __restrict__ out_idx,
                      int N, int K) {
    __shared__ float xs[DT * LDSX];
    __shared__ float es[DT * LDSX];
    __shared__ float sval[BM * 17];
    __shared__ int   sidx[BM * 17];
    const int tid = threadIdx.x;
    const int tx = tid & 15, ty = tid >> 4;
    const int r0 = blockIdx.x * BM;
    float best_val[8]; int best_idx[8];
#pragma unroll
    for (int i = 0; i < 8; ++i) { best_val[i] = 3.4e38f; best_idx[i] = 0; }
    const int nkt = K / BK;
    for (int kt = 0; kt < nkt; ++kt) {
        float acc[8][8];
#pragma unroll
        for (int i = 0; i < 8; ++i)
#pragma unroll
            for (int j = 0; j < 8; ++j) acc[i][j] = 0.f;
        for (int dt = 0; dt < DIM / DT; ++dt) {
            __syncthreads();
#pragma unroll
            for (int k = 0; k < 4; ++k) {
                int l = tid + k * 256, row = l >> 3, q = l & 7;
                const float4 v = *(const float4*)(x + (size_t)(r0 + row) * DIM + dt * DT + q * 4);
                xs[(q * 4 + 0) * LDSX + row] = v.x; xs[(q * 4 + 1) * LDSX + row] = v.y;
                xs[(q * 4 + 2) * LDSX + row] = v.z; xs[(q * 4 + 3) * LDSX + row] = v.w;
            }
#pragma unroll
            for (int k = 0; k < 4; ++k) {
                int l = tid + k * 256, row = l >> 3, q = l & 7;
                const float4 v = *(const float4*)(embed + (size_t)(kt * BK + row) * DIM + dt * DT + q * 4);
                es[(q * 4 + 0) * LDSX + row] = v.x; es[(q * 4 + 1) * LDSX + row] = v.y;
                es[(q * 4 + 2) * LDSX + row] = v.z; es[(q * 4 + 3) * LDSX + row] = v.w;
            }
            __syncthreads();
#pragma unroll
            for (int d = 0; d < DT; ++d) {
                const float4 a0 = *(const float4*)&xs[d * LDSX + 4 * ty];
                const float4 a1 = *(const float4*)&xs[d * LDSX + 4 * ty + 64];
                const float4 b0 = *(const float4*)&es[d * LDSX + 4 * tx];
                const float4 b1 = *(const float4*)&es[d * LDSX + 4 * tx + 64];
                const float a[8] = {a0.x, a0.y, a0.z, a0.w, a1.x, a1.y, a1.z, a1.w};
                const float b[8] = {b0.x, b0.y, b0.z, b0.w, b1.x, b1.y, b1.z, b1.w};
#pragma unroll
                for (int i = 0; i < 8; ++i)
#pragma unroll
                    for (int j = 0; j < 8; ++j) acc[i][j] += a[i] * b[j];
            }
        }
#pragma unroll
        for (int j = 0; j < 8; ++j) {
            const int c = kt * BK + 4 * tx + (j & 3) + 64 * (j >> 2);
            const float eq = e_sq[c];
#pragma unroll
            for (int i = 0; i < 8; ++i) {
                const float s = eq - 2.0f * acc[i][j];
                if (s < best_val[i]) { best_val[i] = s; best_idx[i] = c; }
            }
        }
    }
    __syncthreads();
#pragma unroll
    for (int i = 0; i < 8; ++i) {
        const int r = 4 * ty + (i & 3) + 64 * (i >> 2);
        sval[r * 17 + tx] = best_val[i]; sidx[r * 17 + tx] = best_idx[i];
    }
    __syncthreads();
    if (tid < BM) {
        float bv = sval[tid * 17 + 0]; int bi = sidx[tid * 17 + 0];
#pragma unroll
        for (int t = 1; t < 16; ++t) {
            const float v = sval[tid * 17 + t]; const int ix = sidx[tid * 17 + t];
            if (v < bv || (v == bv && ix < bi)) { bv = v; bi = ix; }
        }
        out_idx[r0 + tid] = (float)bi;
    }
}

__global__ __launch_bounds__(256)
void gather_kernel(const float* __restrict__ embed, const float* __restrict__ idx_f,
                   float* __restrict__ out_q) {
    const int row = blockIdx.x * 2 + (threadIdx.x >> 7);
    const int c = threadIdx.x & 127;
    const int idx = (int)idx_f[row];
    const float4 v = *(const float4*)(embed + (size_t)idx * DIM + c * 4);
    *(float4*)(out_q + (size_t)row * DIM + c * 4) = v;
}

// ================= launch =================
extern "C" void kernel_launch(void* const* d_in, const int* in_sizes, int n_in,
                              void* d_out, int out_size, void* d_ws, size_t ws_size,
                              hipStream_t stream) {
    const float* x     = (const float*)d_in[0];
    const float* embed = (const float*)d_in[1];
    const int N = in_sizes[0] / DIM;   // 65536
    const int K = in_sizes[1] / DIM;   // 2048

    float* out_idx = (float*)d_out;
    float* out_q   = (float*)d_out + N;
    char* ws = (char*)d_ws;

    const size_t off_cand = 8192;                              // after e_sq (K*4)
    const size_t off_eh   = off_cand + (size_t)N * 16;         // cand: N*4 ints
    const size_t need     = off_eh + (size_t)K * DIM * 2;      // eh: K*DIM halfs

    float* e_sq = (float*)ws;
    esq_kernel<<<(K + 3) / 4, 256, 0, stream>>>(embed, e_sq, K);

    if (ws_size >= need && K == 2048 && (N % 128) == 0) {
        _Float16* eh = (_Float16*)(ws + off_eh);
        int* cand = (int*)(ws + off_cand);
        cvt_f16_kernel<<<(K * DIM / 4 + 255) / 256, 256, 0, stream>>>(embed, eh, K * DIM / 4);
        vq_reg_kernel<<<N / 128, 256, 0, stream>>>(x, eh, e_sq, cand);
        verify_gather4_kernel<<<N / 16, 256, 0, stream>>>(x, embed, e_sq, cand, out_idx, out_q);
    } else {
        vq_argmin_kernel<<<N / BM, 256, 0, stream>>>(x, embed, e_sq, out_idx, N, K);
        gather_kernel<<<N / 2, 256, 0, stream>>>(embed, out_idx, out_q);
    }
}